// Round 8
// baseline (216.755 us; speedup 1.0000x reference)
//
#include <hip/hip_runtime.h>
#include <hip/hip_bf16.h>
#include <math.h>

// Problem constants (B=1)
#define TT   192      // sequence length T
#define HH   1024     // hidden H
#define NHH  16       // heads
#define HD   64       // head dim
#define H3   3072     // 3*H
#define QKS  2048     // Q|K buffer row stride (V lives transposed in Vt)
#define VTS  200      // Vt row stride in shorts (padded, 192 used)
#define LN_EPS 1e-5f

// -------------------------------------------------------------------------
// build_edges is numerically dead: edges=softmax(scores,-1) is consumed only
// as edges.sum(-1)==1.0 -> ew constant along attention softmax axis ->
// softmax shift invariance -> output == 2 layers of plain MHA + LN + residual.
//
// Round-8: drop cvt3 entirely. GEMMs stage fp32 A and fp32 weights directly
// to LDS via global_load_lds (16-B chunks are dtype-agnostic) and convert to
// bf16 fragments at LDS-read time with v_cvt_pk_bf16_f32 (same RNE rounding
// as the old pre-pass). Weights are read exactly once (33.5 MB fp32).
// 8 dispatches: 2 x (qkv-gemm -> attn -> proj-gemm -> ln_residual).
// Measured lessons: R6 cross-workgroup threadfence -> L2 invalidate disaster
// (137 us/dispatch @ 39 GB/s) - never fuse across workgroups. R5 split-K
// neutral -> GEMMs are not the bottleneck; floor is harness fill/restore +
// ~2 us/dispatch gaps.
// -------------------------------------------------------------------------

typedef __attribute__((ext_vector_type(4))) float floatx4;
typedef __attribute__((ext_vector_type(8))) short short8;

static __device__ inline unsigned short f2bf(float f) {
    union { float f; unsigned u; } v; v.f = f;
    return (unsigned short)((v.u + 0x7fffu + ((v.u >> 16) & 1u)) >> 16);  // RNE
}

// 8 fp32 -> bf16x8 fragment via packed cvt (RNE)
static __device__ inline short8 cvt8(float4 a, float4 b) {
    union { short8 s; __hip_bfloat162 h[4]; } u;
    u.h[0] = __float22bfloat162_rn(make_float2(a.x, a.y));
    u.h[1] = __float22bfloat162_rn(make_float2(a.z, a.w));
    u.h[2] = __float22bfloat162_rn(make_float2(b.x, b.y));
    u.h[3] = __float22bfloat162_rn(make_float2(b.z, b.w));
    return u.s;
}

#define GLD(gp, lp) __builtin_amdgcn_global_load_lds( \
    (const __attribute__((address_space(1))) void*)(gp), \
    (__attribute__((address_space(3))) void*)(lp), 16, 0, 0)

// C[M,N] = A[M,K] @ B[N,K]^T + bias[N], A and B fp32 row-major, K = 1024.
// Tile 64x64, BK=128 x 8 iters; A,B staged fp32 (32 KB each) via
// global_load_lds; fragments converted to bf16 at LDS-read time.
// XOR swizzle: phys 16-B chunk = logical ^ (row & 15) keeps the
// lane-contiguous staging and the per-fragment float4 reads conflict-free
// (2-way bank aliasing only, which is free).
// QKV_EPI=1: N=3072; cols < 2H -> bf16 Q|K at row stride QKS, cols >= 2H ->
// transposed bf16 Vt[d][t].  QKV_EPI=0: N=1024; fp32 C with bias.
template <int QKV_EPI>
__global__ __launch_bounds__(256) void gemm_f32(const float* __restrict__ A,
                                                const float* __restrict__ Bw,
                                                const float* __restrict__ bias,
                                                unsigned short* __restrict__ qkvQK,
                                                unsigned short* __restrict__ Vt,
                                                float* __restrict__ C)
{
    const int K = HH;
    const int N = QKV_EPI ? H3 : HH;
    __shared__ __align__(16) float As[64 * 128];   // 32 KB
    __shared__ __align__(16) float Bs[64 * 128];   // 32 KB
    const int tid  = threadIdx.x;
    const int w    = tid >> 6;
    const int lane = tid & 63;
    const int quad = lane >> 4;
    const int l16  = lane & 15;
    const int m0 = blockIdx.y * 64;
    const int n0 = blockIdx.x * 64;

    // staging: GLD g covers rows {2g, 2g+1} (512 B each); lane l -> row
    // 2g+(l>>5), phys slot l&31, source chunk (l&31) ^ (row&15).
    const int rin  = lane >> 5;
    const int slot = lane & 31;

    int aoff[8], boff[8];
    #pragma unroll
    for (int j = 0; j < 8; ++j) {
        const int g   = w * 8 + j;
        const int row = 2 * g + rin;
        const int ch  = slot ^ (row & 15);
        aoff[j] = (m0 + row) * K + ch * 4;
        boff[j] = (n0 + row) * K + ch * 4;
    }

    floatx4 acc[4] = {};
    for (int it = 0; it < 8; ++it) {
        const int k0 = it << 7;
        __syncthreads();                  // prev iteration's LDS reads done
        #pragma unroll
        for (int j = 0; j < 8; ++j) {
            const int g = w * 8 + j;
            GLD(A  + aoff[j] + k0, As + g * 256);
            GLD(Bw + boff[j] + k0, Bs + g * 256);
        }
        __syncthreads();                  // vmcnt(0) drain: tile resident

        #pragma unroll
        for (int kc = 0; kc < 4; ++kc) {
            const int c0 = kc * 8 + quad * 2;      // logical 16-B chunk pair
            const int pa = (c0 ^ l16) * 4;
            const int pb = ((c0 + 1) ^ l16) * 4;
            const float4 a0 = *(const float4*)&As[(w * 16 + l16) * 128 + pa];
            const float4 a1 = *(const float4*)&As[(w * 16 + l16) * 128 + pb];
            const short8 af = cvt8(a0, a1);
            #pragma unroll
            for (int nt = 0; nt < 4; ++nt) {
                const float4 b0 = *(const float4*)&Bs[(nt * 16 + l16) * 128 + pa];
                const float4 b1 = *(const float4*)&Bs[(nt * 16 + l16) * 128 + pb];
                acc[nt] = __builtin_amdgcn_mfma_f32_16x16x32_bf16(
                    af, cvt8(b0, b1), acc[nt], 0, 0, 0);
            }
        }
    }

    // C/D layout: col = lane&15, row = quad*4 + reg
    #pragma unroll
    for (int nt = 0; nt < 4; ++nt) {
        const int col = n0 + nt * 16 + l16;
        const float bz = bias[col];
        if (QKV_EPI && col >= 2 * HH) {   // V third -> transposed bf16 Vt[d][t]
            const int d = col - 2 * HH;
            const int t = m0 + w * 16 + quad * 4;
            ushort4 pk;
            pk.x = f2bf(acc[nt][0] + bz);
            pk.y = f2bf(acc[nt][1] + bz);
            pk.z = f2bf(acc[nt][2] + bz);
            pk.w = f2bf(acc[nt][3] + bz);
            *(ushort4*)&Vt[(size_t)d * VTS + t] = pk;
        } else if (QKV_EPI) {
            #pragma unroll
            for (int r = 0; r < 4; ++r) {
                const int row = m0 + w * 16 + quad * 4 + r;
                qkvQK[(size_t)row * QKS + col] = f2bf(acc[nt][r] + bz);
            }
        } else {
            #pragma unroll
            for (int r = 0; r < 4; ++r) {
                const int row = m0 + w * 16 + quad * 4 + r;
                C[(size_t)row * N + col] = acc[nt][r] + bz;
            }
        }
    }
}

// Fused attention: one block (256 thr) per (head, 64-query tile).
// bf16 Q/K/Vt in; fp32 O out (feeds fp32-A proj GEMM).
__global__ __launch_bounds__(256) void attn_fused(const unsigned short* __restrict__ qkv,
                                                  const unsigned short* __restrict__ VtG,
                                                  float* __restrict__ Oout)
{
    __shared__ __align__(16) unsigned short Qs[64 * 64];     //  8 KB swizzled
    __shared__ __align__(16) unsigned short Ks[192 * 64];    // 24 KB swizzled
    __shared__ __align__(16) unsigned short Vts[64 * VTS];   // 25 KB flat copy
    __shared__ __align__(16) unsigned short Ps[64 * VTS];    // 25 KB padded

    const int h  = blockIdx.x;
    const int q0 = blockIdx.y * 64;
    const int tid  = threadIdx.x;
    const int w    = tid >> 6;
    const int lane = tid & 63;
    const int quad = lane >> 4;
    const int l16  = lane & 15;

    const int rin = lane >> 3;          // 0..7 row within an 8-row GLD
    const int ch8 = (lane & 7) ^ rin;   // swizzled source chunk

    #pragma unroll
    for (int j = 0; j < 2; ++j) {
        const int g = w * 2 + j;
        GLD(qkv + (size_t)(q0 + g * 8 + rin) * QKS + h * HD + ch8 * 8, Qs + g * 512);
    }
    #pragma unroll
    for (int j = 0; j < 6; ++j) {
        const int g = w * 6 + j;
        GLD(qkv + (size_t)(g * 8 + rin) * QKS + HH + h * HD + ch8 * 8, Ks + g * 512);
    }
    #pragma unroll
    for (int j = 0; j < 7; ++j) {
        const int g = w * 7 + j;                       // 0..27
        if (g < 25)                                    // 64*VTS*2 B = 25 KiB
            GLD(VtG + (size_t)h * HD * VTS + g * 512 + lane * 8, Vts + g * 512);
    }
    __syncthreads();

    // ---- S = Q K^T (wave w owns q rows w*16..w*16+15) ----
    floatx4 accs[12] = {};
    #pragma unroll
    for (int kc = 0; kc < 2; ++kc) {
        const int s = (kc * 4 + quad) ^ (l16 & 7);
        short8 af = *(const short8*)&Qs[(w * 16 + l16) * 64 + s * 8];
        #pragma unroll
        for (int nt = 0; nt < 12; ++nt) {
            short8 bf = *(const short8*)&Ks[(nt * 16 + l16) * 64 + s * 8];
            accs[nt] = __builtin_amdgcn_mfma_f32_16x16x32_bf16(af, bf, accs[nt], 0, 0, 0);
        }
    }

    // ---- softmax over 192 keys (12 frags x 16 lanes), scale 1/8 ----
    float invr[4];
    #pragma unroll
    for (int r = 0; r < 4; ++r) {
        float m = accs[0][r];
        #pragma unroll
        for (int nt = 1; nt < 12; ++nt) m = fmaxf(m, accs[nt][r]);
        #pragma unroll
        for (int off = 1; off < 16; off <<= 1) m = fmaxf(m, __shfl_xor(m, off));
        float sum = 0.f;
        #pragma unroll
        for (int nt = 0; nt < 12; ++nt) {
            const float p = __expf((accs[nt][r] - m) * 0.125f);
            accs[nt][r] = p;
            sum += p;
        }
        #pragma unroll
        for (int off = 1; off < 16; off <<= 1) sum += __shfl_xor(sum, off);
        invr[r] = 1.f / sum;
        const int row = w * 16 + quad * 4 + r;
        #pragma unroll
        for (int nt = 0; nt < 12; ++nt)
            Ps[row * VTS + nt * 16 + l16] = f2bf(accs[nt][r]);
    }
    __syncthreads();

    // ---- O = P V  (contract over keys; Vt rows are d, cols are keys) ----
    floatx4 acco[4] = {};
    #pragma unroll
    for (int kc = 0; kc < 6; ++kc) {
        short8 af = *(const short8*)&Ps[(w * 16 + l16) * VTS + kc * 32 + quad * 8];
        #pragma unroll
        for (int nt = 0; nt < 4; ++nt) {
            short8 bf = *(const short8*)&Vts[(nt * 16 + l16) * VTS + kc * 32 + quad * 8];
            acco[nt] = __builtin_amdgcn_mfma_f32_16x16x32_bf16(af, bf, acco[nt], 0, 0, 0);
        }
    }

    #pragma unroll
    for (int nt = 0; nt < 4; ++nt) {
        const int d = h * HD + nt * 16 + l16;
        #pragma unroll
        for (int r = 0; r < 4; ++r) {
            const int q = q0 + w * 16 + quad * 4 + r;
            Oout[(size_t)q * HH + d] = acco[nt][r] * invr[r];
        }
    }
}

// xout = xin + LN(y)*g + b  (fp32 only; one block per row)
__global__ __launch_bounds__(256) void ln_residual(const float* __restrict__ y,
                                                   const float* __restrict__ xin,
                                                   const float* __restrict__ g,
                                                   const float* __restrict__ b,
                                                   float* __restrict__ xout)
{
    const int row = blockIdx.x;
    const int tid = threadIdx.x;
    const size_t base = (size_t)row * HH + tid * 4;

    const float4 v = *(const float4*)&y[base];
    float s  = v.x + v.y + v.z + v.w;
    float sq = v.x * v.x + v.y * v.y + v.z * v.z + v.w * v.w;

    #pragma unroll
    for (int off = 32; off > 0; off >>= 1) {
        s  += __shfl_down(s,  off);
        sq += __shfl_down(sq, off);
    }
    __shared__ float ws[4], wq[4];
    const int wave = tid >> 6;
    if ((tid & 63) == 0) { ws[wave] = s; wq[wave] = sq; }
    __syncthreads();
    float ts = 0.f, tq = 0.f;
    #pragma unroll
    for (int w = 0; w < 4; ++w) { ts += ws[w]; tq += wq[w]; }

    const float mean = ts * (1.f / HH);
    const float var  = tq * (1.f / HH) - mean * mean;
    const float r    = rsqrtf(var + LN_EPS);

    const float4 xi = *(const float4*)&xin[base];
    const float4 gg = *(const float4*)&g[tid * 4];
    const float4 bb = *(const float4*)&b[tid * 4];
    float4 o;
    o.x = xi.x + (v.x - mean) * r * gg.x + bb.x;
    o.y = xi.y + (v.y - mean) * r * gg.y + bb.y;
    o.z = xi.z + (v.z - mean) * r * gg.z + bb.z;
    o.w = xi.w + (v.w - mean) * r * gg.w + bb.w;
    *(float4*)&xout[base] = o;
}

extern "C" void kernel_launch(void* const* d_in, const int* in_sizes, int n_in,
                              void* d_out, int out_size, void* d_ws, size_t ws_size,
                              hipStream_t stream)
{
    const float* nodes     = (const float*)d_in[0];
    const float* mha_in_w  = (const float*)d_in[14];   // [2, 3H, H]
    const float* mha_in_b  = (const float*)d_in[15];   // [2, 3H]
    const float* mha_out_w = (const float*)d_in[16];   // [2, H, H]
    const float* mha_out_b = (const float*)d_in[17];   // [2, H]
    const float* mha_ln_g  = (const float*)d_in[18];   // [2, H]
    const float* mha_ln_b  = (const float*)d_in[19];   // [2, H]
    float* out = (float*)d_out;

    // ---- ws carve (bf16 region then fp32 region; all 16-B aligned) ----
    unsigned short* u = (unsigned short*)d_ws;
    unsigned short* bf_qk = u;  u += TT * QKS;          // bf16 Q|K
    unsigned short* Vt    = u;  u += HH * VTS;          // [1024][200] bf16
    float* f = (float*)u;
    float* O     = f;  f += TT * HH;                    // fp32 attn output
    float* Pproj = f;  f += TT * HH;                    // fp32 proj scratch
    float* x1    = f;  f += TT * HH;

    const float* x_f = nodes;
    for (int l = 0; l < 2; ++l) {
        float* xout = (l == 0) ? x1 : out;

        gemm_f32<1><<<dim3(H3 / 64, TT / 64), 256, 0, stream>>>(
            x_f, mha_in_w + (size_t)l * H3 * HH, mha_in_b + l * H3,
            bf_qk, Vt, nullptr);

        attn_fused<<<dim3(NHH, TT / 64), 256, 0, stream>>>(bf_qk, Vt, O);

        gemm_f32<0><<<dim3(HH / 64, TT / 64), 256, 0, stream>>>(
            O, mha_out_w + (size_t)l * HH * HH, mha_out_b + l * HH,
            nullptr, nullptr, Pproj);

        ln_residual<<<TT, 256, 0, stream>>>(
            Pproj, x_f, mha_ln_g + l * HH, mha_ln_b + l * HH, xout);

        x_f = xout;
    }
}

// Round 9
// 169.798 us; speedup vs baseline: 1.2765x; 1.2765x over previous
//
#include <hip/hip_runtime.h>
#include <math.h>

// Problem constants (B=1)
#define TT   192      // sequence length T
#define HH   1024     // hidden H
#define NHH  16       // heads
#define HD   64       // head dim
#define H3   3072     // 3*H
#define QKS  2048     // Q|K buffer row stride (V lives transposed in Vt)
#define VTS  200      // Vt row stride in shorts (padded, 192 used)
#define LN_EPS 1e-5f

// -------------------------------------------------------------------------
// build_edges is numerically dead: edges=softmax(scores,-1) is consumed only
// as edges.sum(-1)==1.0 -> ew constant along attention softmax axis ->
// softmax shift invariance -> output == 2 layers of plain MHA + LN + residual.
//
// Round-9: EXACT revert to round-7 (measured best, 170.0 µs; structure
// independently measured twice at 170.0/170.1).
// Measured ledger of failed alternatives:
//   R5 split-K          +7.6 µs  (GEMMs latency-floor-bound, not BW/occupancy)
//   R6 threadfence fuse +235 µs  (cross-XCD L2 writeback/invalidate: 39 GB/s)
//   R8 inline fp32 cvt  +47 µs   (2x LDS -> less occupancy, 2x barrier drains,
//                                 cvt back on LDS->MFMA critical path)
// Remaining time = harness floor (256 MiB ws re-poison fill ~42 µs @80% HBM
// + input restores + ~2 µs/dispatch ordered gaps) + ~20 µs kernel work.
// -------------------------------------------------------------------------

typedef __attribute__((ext_vector_type(4))) float floatx4;
typedef __attribute__((ext_vector_type(8))) short short8;

static __device__ inline unsigned short f2bf(float f) {
    union { float f; unsigned u; } v; v.f = f;
    return (unsigned short)((v.u + 0x7fffu + ((v.u >> 16) & 1u)) >> 16);  // RNE
}

// fused fp32->bf16 of the three sources in one dispatch
__global__ __launch_bounds__(256) void cvt3(const float* __restrict__ a, int na4,
                                            const float* __restrict__ b, int nb4,
                                            const float* __restrict__ c, int nc4,
                                            unsigned short* __restrict__ da,
                                            unsigned short* __restrict__ db,
                                            unsigned short* __restrict__ dc)
{
    int j = blockIdx.x * 256 + threadIdx.x;
    const float* s; unsigned short* d;
    if (j < na4)                 { s = a; d = da; }
    else if ((j -= na4) < nb4)   { s = b; d = db; }
    else if ((j -= nb4) < nc4)   { s = c; d = dc; }
    else return;
    float4 v = ((const float4*)s)[j];
    ushort4 o;
    o.x = f2bf(v.x); o.y = f2bf(v.y); o.z = f2bf(v.z); o.w = f2bf(v.w);
    ((ushort4*)d)[j] = o;
}

#define GLD(gp, lp) __builtin_amdgcn_global_load_lds( \
    (const __attribute__((address_space(1))) void*)(gp), \
    (__attribute__((address_space(3))) void*)(lp), 16, 0, 0)

// qkv GEMM: [192,3072] = A[192,1024] @ W[3072,1024]^T + bias (bf16 in/out).
// Tile 64x64, BK=256 x 4 iters. Cols < 2H -> bf16 Q|K at row stride QKS;
// cols >= 2H -> transposed bf16 Vt[d][t]. XOR swizzle keeps global_load_lds
// staging and ds_read_b128 fragment reads conflict-free with unpadded rows.
__global__ __launch_bounds__(256) void gemm_qkv(const unsigned short* __restrict__ A,
                                                const unsigned short* __restrict__ Bw,
                                                const float* __restrict__ bias,
                                                unsigned short* __restrict__ qkvQK,
                                                unsigned short* __restrict__ Vt)
{
    const int K = HH;
    __shared__ __align__(16) unsigned short As[64 * 256];
    __shared__ __align__(16) unsigned short Bs[64 * 256];
    const int tid  = threadIdx.x;
    const int w    = tid >> 6;
    const int lane = tid & 63;
    const int quad = lane >> 4;
    const int l16  = lane & 15;
    const int m0 = blockIdx.y * 64;
    const int n0 = blockIdx.x * 64;

    const int rin = lane >> 5;       // row within a 2-row GLD
    const int cl  = lane & 31;       // logical chunk slot

    int aoff[8], boff[8];
    #pragma unroll
    for (int j = 0; j < 8; ++j) {
        const int g   = w * 8 + j;
        const int row = 2 * g + rin;
        const int ch  = cl ^ (row & 7);
        aoff[j] = (m0 + row) * K + ch * 8;
        boff[j] = (n0 + row) * K + ch * 8;
    }

    floatx4 acc[4] = {};
    for (int it = 0; it < 4; ++it) {
        const int k0 = it << 8;
        __syncthreads();
        #pragma unroll
        for (int j = 0; j < 8; ++j) {
            const int g = w * 8 + j;
            GLD(A  + aoff[j] + k0, As + g * 512);
            GLD(Bw + boff[j] + k0, Bs + g * 512);
        }
        __syncthreads();
        #pragma unroll
        for (int kc = 0; kc < 8; ++kc) {
            const int s = (kc * 4 + quad) ^ (l16 & 7);
            short8 af = *(const short8*)&As[(w * 16 + l16) * 256 + s * 8];
            #pragma unroll
            for (int nt = 0; nt < 4; ++nt) {
                short8 bf = *(const short8*)&Bs[(nt * 16 + l16) * 256 + s * 8];
                acc[nt] = __builtin_amdgcn_mfma_f32_16x16x32_bf16(af, bf, acc[nt], 0, 0, 0);
            }
        }
    }

    // C/D layout: col = lane&15, row = quad*4 + reg
    #pragma unroll
    for (int nt = 0; nt < 4; ++nt) {
        const int col = n0 + nt * 16 + l16;
        const float bz = bias[col];
        if (col >= 2 * HH) {         // V third -> transposed bf16 Vt[d][t]
            const int d = col - 2 * HH;
            const int t = m0 + w * 16 + quad * 4;
            ushort4 pk;
            pk.x = f2bf(acc[nt][0] + bz);
            pk.y = f2bf(acc[nt][1] + bz);
            pk.z = f2bf(acc[nt][2] + bz);
            pk.w = f2bf(acc[nt][3] + bz);
            *(ushort4*)&Vt[(size_t)d * VTS + t] = pk;
        } else {
            #pragma unroll
            for (int r = 0; r < 4; ++r) {
                const int row = m0 + w * 16 + quad * 4 + r;
                qkvQK[(size_t)row * QKS + col] = f2bf(acc[nt][r] + bz);
            }
        }
    }
}

// out-proj GEMM: [192,1024] = O[192,1024] @ W[1024,1024]^T (bf16 in, fp32 out,
// bias added here). Same structure as gemm_qkv.
__global__ __launch_bounds__(256) void gemm_proj(const unsigned short* __restrict__ A,
                                                 const unsigned short* __restrict__ Bw,
                                                 const float* __restrict__ bias,
                                                 float* __restrict__ C)
{
    const int K = HH, N = HH;
    __shared__ __align__(16) unsigned short As[64 * 256];
    __shared__ __align__(16) unsigned short Bs[64 * 256];
    const int tid  = threadIdx.x;
    const int w    = tid >> 6;
    const int lane = tid & 63;
    const int quad = lane >> 4;
    const int l16  = lane & 15;
    const int m0 = blockIdx.y * 64;
    const int n0 = blockIdx.x * 64;

    const int rin = lane >> 5;
    const int cl  = lane & 31;

    int aoff[8], boff[8];
    #pragma unroll
    for (int j = 0; j < 8; ++j) {
        const int g   = w * 8 + j;
        const int row = 2 * g + rin;
        const int ch  = cl ^ (row & 7);
        aoff[j] = (m0 + row) * K + ch * 8;
        boff[j] = (n0 + row) * K + ch * 8;
    }

    floatx4 acc[4] = {};
    for (int it = 0; it < 4; ++it) {
        const int k0 = it << 8;
        __syncthreads();
        #pragma unroll
        for (int j = 0; j < 8; ++j) {
            const int g = w * 8 + j;
            GLD(A  + aoff[j] + k0, As + g * 512);
            GLD(Bw + boff[j] + k0, Bs + g * 512);
        }
        __syncthreads();
        #pragma unroll
        for (int kc = 0; kc < 8; ++kc) {
            const int s = (kc * 4 + quad) ^ (l16 & 7);
            short8 af = *(const short8*)&As[(w * 16 + l16) * 256 + s * 8];
            #pragma unroll
            for (int nt = 0; nt < 4; ++nt) {
                short8 bf = *(const short8*)&Bs[(nt * 16 + l16) * 256 + s * 8];
                acc[nt] = __builtin_amdgcn_mfma_f32_16x16x32_bf16(af, bf, acc[nt], 0, 0, 0);
            }
        }
    }

    #pragma unroll
    for (int nt = 0; nt < 4; ++nt) {
        const int col = n0 + nt * 16 + l16;
        const float bz = bias[col];
        #pragma unroll
        for (int r = 0; r < 4; ++r) {
            const int row = m0 + w * 16 + quad * 4 + r;
            C[(size_t)row * N + col] = acc[nt][r] + bz;
        }
    }
}

// Fused attention: one block (256 thr) per (head, 64-query tile).
__global__ __launch_bounds__(256) void attn_fused(const unsigned short* __restrict__ qkv,
                                                  const unsigned short* __restrict__ VtG,
                                                  unsigned short* __restrict__ Oout)
{
    __shared__ __align__(16) unsigned short Qs[64 * 64];     //  8 KB swizzled
    __shared__ __align__(16) unsigned short Ks[192 * 64];    // 24 KB swizzled
    __shared__ __align__(16) unsigned short Vts[64 * VTS];   // 25 KB flat copy
    __shared__ __align__(16) unsigned short Ps[64 * VTS];    // 25 KB padded

    const int h  = blockIdx.x;
    const int q0 = blockIdx.y * 64;
    const int tid  = threadIdx.x;
    const int w    = tid >> 6;
    const int lane = tid & 63;
    const int quad = lane >> 4;
    const int l16  = lane & 15;

    const int rin = lane >> 3;          // 0..7 row within an 8-row GLD
    const int ch8 = (lane & 7) ^ rin;   // swizzled source chunk

    #pragma unroll
    for (int j = 0; j < 2; ++j) {
        const int g = w * 2 + j;
        GLD(qkv + (size_t)(q0 + g * 8 + rin) * QKS + h * HD + ch8 * 8, Qs + g * 512);
    }
    #pragma unroll
    for (int j = 0; j < 6; ++j) {
        const int g = w * 6 + j;
        GLD(qkv + (size_t)(g * 8 + rin) * QKS + HH + h * HD + ch8 * 8, Ks + g * 512);
    }
    #pragma unroll
    for (int j = 0; j < 7; ++j) {
        const int g = w * 7 + j;                       // 0..27
        if (g < 25)                                    // 64*VTS*2 B = 25 KiB
            GLD(VtG + (size_t)h * HD * VTS + g * 512 + lane * 8, Vts + g * 512);
    }
    __syncthreads();

    // ---- S = Q K^T (wave w owns q rows w*16..w*16+15) ----
    floatx4 accs[12] = {};
    #pragma unroll
    for (int kc = 0; kc < 2; ++kc) {
        const int s = (kc * 4 + quad) ^ (l16 & 7);
        short8 af = *(const short8*)&Qs[(w * 16 + l16) * 64 + s * 8];
        #pragma unroll
        for (int nt = 0; nt < 12; ++nt) {
            short8 bf = *(const short8*)&Ks[(nt * 16 + l16) * 64 + s * 8];
            accs[nt] = __builtin_amdgcn_mfma_f32_16x16x32_bf16(af, bf, accs[nt], 0, 0, 0);
        }
    }

    // ---- softmax over 192 keys (12 frags x 16 lanes), scale 1/8 ----
    float invr[4];
    #pragma unroll
    for (int r = 0; r < 4; ++r) {
        float m = accs[0][r];
        #pragma unroll
        for (int nt = 1; nt < 12; ++nt) m = fmaxf(m, accs[nt][r]);
        #pragma unroll
        for (int off = 1; off < 16; off <<= 1) m = fmaxf(m, __shfl_xor(m, off));
        float sum = 0.f;
        #pragma unroll
        for (int nt = 0; nt < 12; ++nt) {
            const float p = __expf((accs[nt][r] - m) * 0.125f);
            accs[nt][r] = p;
            sum += p;
        }
        #pragma unroll
        for (int off = 1; off < 16; off <<= 1) sum += __shfl_xor(sum, off);
        invr[r] = 1.f / sum;
        const int row = w * 16 + quad * 4 + r;
        #pragma unroll
        for (int nt = 0; nt < 12; ++nt)
            Ps[row * VTS + nt * 16 + l16] = f2bf(accs[nt][r]);
    }
    __syncthreads();

    // ---- O = P V  (contract over keys; Vt rows are d, cols are keys) ----
    floatx4 acco[4] = {};
    #pragma unroll
    for (int kc = 0; kc < 6; ++kc) {
        short8 af = *(const short8*)&Ps[(w * 16 + l16) * VTS + kc * 32 + quad * 8];
        #pragma unroll
        for (int nt = 0; nt < 4; ++nt) {
            short8 bf = *(const short8*)&Vts[(nt * 16 + l16) * VTS + kc * 32 + quad * 8];
            acco[nt] = __builtin_amdgcn_mfma_f32_16x16x32_bf16(af, bf, acco[nt], 0, 0, 0);
        }
    }

    #pragma unroll
    for (int nt = 0; nt < 4; ++nt) {
        const int d = h * HD + nt * 16 + l16;
        #pragma unroll
        for (int r = 0; r < 4; ++r) {
            const int q = q0 + w * 16 + quad * 4 + r;
            Oout[(size_t)q * HH + d] = f2bf(acco[nt][r] * invr[r]);
        }
    }
}

// xout = xin + LN(y)*g + b ; fp32 out (+ optional bf16 for next layer's GEMM)
template <int WRITE_BF>
__global__ __launch_bounds__(256) void ln_residual(const float* __restrict__ y,
                                                   const float* __restrict__ xin,
                                                   const float* __restrict__ g,
                                                   const float* __restrict__ b,
                                                   float* __restrict__ xout,
                                                   unsigned short* __restrict__ xout_bf)
{
    const int row = blockIdx.x;
    const int tid = threadIdx.x;
    const size_t base = (size_t)row * HH + tid * 4;

    const float4 v = *(const float4*)&y[base];
    float s  = v.x + v.y + v.z + v.w;
    float sq = v.x * v.x + v.y * v.y + v.z * v.z + v.w * v.w;

    #pragma unroll
    for (int off = 32; off > 0; off >>= 1) {
        s  += __shfl_down(s,  off);
        sq += __shfl_down(sq, off);
    }
    __shared__ float ws[4], wq[4];
    const int wave = tid >> 6;
    if ((tid & 63) == 0) { ws[wave] = s; wq[wave] = sq; }
    __syncthreads();
    float ts = 0.f, tq = 0.f;
    #pragma unroll
    for (int w = 0; w < 4; ++w) { ts += ws[w]; tq += wq[w]; }

    const float mean = ts * (1.f / HH);
    const float var  = tq * (1.f / HH) - mean * mean;
    const float r    = rsqrtf(var + LN_EPS);

    const float4 xi = *(const float4*)&xin[base];
    const float4 gg = *(const float4*)&g[tid * 4];
    const float4 bb = *(const float4*)&b[tid * 4];
    float4 o;
    o.x = xi.x + (v.x - mean) * r * gg.x + bb.x;
    o.y = xi.y + (v.y - mean) * r * gg.y + bb.y;
    o.z = xi.z + (v.z - mean) * r * gg.z + bb.z;
    o.w = xi.w + (v.w - mean) * r * gg.w + bb.w;
    *(float4*)&xout[base] = o;
    if (WRITE_BF) {
        ushort4 ob;
        ob.x = f2bf(o.x); ob.y = f2bf(o.y); ob.z = f2bf(o.z); ob.w = f2bf(o.w);
        *(ushort4*)&xout_bf[base] = ob;
    }
}

extern "C" void kernel_launch(void* const* d_in, const int* in_sizes, int n_in,
                              void* d_out, int out_size, void* d_ws, size_t ws_size,
                              hipStream_t stream)
{
    const float* nodes     = (const float*)d_in[0];
    const float* mha_in_w  = (const float*)d_in[14];   // [2, 3H, H]
    const float* mha_in_b  = (const float*)d_in[15];   // [2, 3H]
    const float* mha_out_w = (const float*)d_in[16];   // [2, H, H]
    const float* mha_out_b = (const float*)d_in[17];   // [2, H]
    const float* mha_ln_g  = (const float*)d_in[18];   // [2, H]
    const float* mha_ln_b  = (const float*)d_in[19];   // [2, H]
    float* out = (float*)d_out;

    // ---- ws carve (bf16 region then fp32 region; all 16-B aligned) ----
    unsigned short* u = (unsigned short*)d_ws;
    unsigned short* bf_inW   = u;  u += 2 * H3 * HH;
    unsigned short* bf_outW  = u;  u += 2 * HH * HH;
    unsigned short* bf_nodes = u;  u += TT * HH;
    unsigned short* bf_x1    = u;  u += TT * HH;
    unsigned short* bf_qk    = u;  u += TT * QKS;       // Q|K only
    unsigned short* bf_o     = u;  u += TT * HH;
    unsigned short* Vt       = u;  u += HH * VTS;       // [1024][200] bf16
    float* f = (float*)u;
    float* Pproj = f;  f += TT * HH;                    // fp32 proj scratch
    float* x1    = f;  f += TT * HH;

    // ---- one-time fp32 -> bf16 (in_w | out_w | nodes) in one dispatch ----
    {
        const int na4 = (2 * H3 * HH) / 4;
        const int nb4 = (2 * HH * HH) / 4;
        const int nc4 = (TT * HH) / 4;
        const int tot = na4 + nb4 + nc4;
        cvt3<<<(tot + 255) / 256, 256, 0, stream>>>(
            mha_in_w, na4, mha_out_w, nb4, nodes, nc4, bf_inW, bf_outW, bf_nodes);
    }

    const float* x_f = nodes;
    const unsigned short* x_bf = bf_nodes;
    for (int l = 0; l < 2; ++l) {
        float* xout = (l == 0) ? x1 : out;

        gemm_qkv<<<dim3(H3 / 64, TT / 64), 256, 0, stream>>>(
            x_bf, bf_inW + (size_t)l * H3 * HH, mha_in_b + l * H3, bf_qk, Vt);

        attn_fused<<<dim3(NHH, TT / 64), 256, 0, stream>>>(bf_qk, Vt, bf_o);

        gemm_proj<<<dim3(HH / 64, TT / 64), 256, 0, stream>>>(
            bf_o, bf_outW + (size_t)l * HH * HH, mha_out_b + l * HH, Pproj);

        if (l == 0)
            ln_residual<1><<<TT, 256, 0, stream>>>(
                Pproj, x_f, mha_ln_g, mha_ln_b, xout, bf_x1);
        else
            ln_residual<0><<<TT, 256, 0, stream>>>(
                Pproj, x_f, mha_ln_g + HH, mha_ln_b + HH, xout, nullptr);

        x_f = xout;
        x_bf = bf_x1;
    }
}